// Round 6
// baseline (36.162 us; speedup 1.0000x reference)
//
#include <hip/hip_runtime.h>

#define D_MODEL   256
#define NUM_TYPES 7
#define BATCH     2
#define NLANES    512

typedef _Float16  f16x8   __attribute__((ext_vector_type(8)));
typedef float     floatx4 __attribute__((ext_vector_type(4)));

// ws layout: Hi16 @ 0 (1024*256 f16 = 512 KB), Hj16 @ 512 KB (512 KB)
// Hi16[b*512+i][k] = (x@W1a + b1)[i][k] in f16 ; Hj16 = (x@W1b) in f16.

// ---------------- Kernel 1: H16 = f16(x @ [W1a|W1b] (+b1)) via f16 MFMA ----------
// (unchanged from round 5 — proven; its share of the total is measured this round)
__global__ __launch_bounds__(256) void k1_mfma(
    const float* __restrict__ x, const float* __restrict__ W1,
    const float* __restrict__ b1, _Float16* __restrict__ Hi16,
    _Float16* __restrict__ Hj16)
{
    const int tid  = threadIdx.x, lane = tid & 63, w = tid >> 6;
    const int nt   = blockIdx.x;                  // 0..31 ; half = nt>>4
    const int half = nt >> 4;
    const int nc   = (nt & 15) * 16;              // n base within the half
    const int m0   = (blockIdx.y * 4 + w) * 16;   // row-tile base (0..1008)
    const int jr   = lane & 15, g = lane >> 4, ks = g * 8;

    const float* xrow = x + (size_t)(m0 + jr) * D_MODEL + ks;                   // +kc*32
    const float* wb   = W1 + (size_t)(half * D_MODEL + ks) * D_MODEL + nc + jr; // +kc*32*256, +e*256

    floatx4 acc = {0.f, 0.f, 0.f, 0.f};
    #pragma unroll
    for (int kc = 0; kc < 8; ++kc) {
        const float4 qa = *(const float4*)(xrow + kc * 32);
        const float4 qb = *(const float4*)(xrow + kc * 32 + 4);
        f16x8 a, bfr;
        a[0] = (_Float16)qa.x; a[1] = (_Float16)qa.y;
        a[2] = (_Float16)qa.z; a[3] = (_Float16)qa.w;
        a[4] = (_Float16)qb.x; a[5] = (_Float16)qb.y;
        a[6] = (_Float16)qb.z; a[7] = (_Float16)qb.w;
        const float* wp = wb + (size_t)(kc * 32) * D_MODEL;
        #pragma unroll
        for (int e = 0; e < 8; ++e)
            bfr[e] = (_Float16)wp[(size_t)e * D_MODEL];
        acc = __builtin_amdgcn_mfma_f32_16x16x32_f16(a, bfr, acc, 0, 0, 0);
    }

    _Float16* Hb = half ? Hj16 : Hi16;
    const float bias = half ? 0.f : b1[nc + jr];
    #pragma unroll
    for (int r = 0; r < 4; ++r)
        Hb[(size_t)(m0 + g * 4 + r) * D_MODEL + nc + jr] = (_Float16)(acc[r] + bias);
}

// ---------------- Kernel 2: out[b,i,j,:] = relu(Hi[i]+Hj[j]) @ W2 + b2 ----------
// Block: 32 j x 32 i, 512 threads = 8 waves (2 j-groups x 4 i-groups).
// Hj tile in LDS [32][520] f16 (1040B row == 16B mod 128 -> diagonal, bank-even).
// Per wave: hj frags preloaded ONCE to regs (32 VGPR), reused across 8 i.
// Per i: 8 batched global loads (hir[8]) -> one wait -> 8x(pk-add,pk-max,MFMA).
// Output chunks per (block,i-row) = 32j*28B = 896B = 7 full L2 lines -> exact writes.
__global__ __launch_bounds__(512, 4) void k2_pair(
    const _Float16* __restrict__ Hi16, const _Float16* __restrict__ Hj16,
    const float* __restrict__ W2, const float* __restrict__ b2,
    float* __restrict__ out)
{
    __shared__ _Float16 hjs[32 * 520];   // 33,280 B

    const int tid  = threadIdx.x;        // 0..511
    const int lane = tid & 63, w = tid >> 6;
    const int jg   = w & 1, ig = w >> 1; // wave: 16 j's (jg), 8 i's (ig)
    const int b    = blockIdx.z;
    const int j0   = blockIdx.x * 32;
    const int i0   = blockIdx.y * 32;

    // ---- stage Hj rows j0..j0+31 (16 KB): 2 x 16B per thread, coalesced ----
    {
        const int r = tid >> 4, c = tid & 15;
        const _Float16* src = Hj16 + (size_t)(b * NLANES + j0 + r) * D_MODEL + c * 8;
        _Float16* dst = hjs + r * 520 + c * 8;
        *(f16x8*)dst         = *(const f16x8*)src;
        *(f16x8*)(dst + 128) = *(const f16x8*)(src + 128);
    }

    // ---- W2^T A-frags + bias (global, L2-hot; overlaps barrier wait) ----
    const int t = lane & 15, g = lane >> 4, ks = g * 8;
    f16x8 w2r[8];
    #pragma unroll
    for (int kc = 0; kc < 8; ++kc) {
        #pragma unroll
        for (int e = 0; e < 8; ++e) {
            const int k = kc * 32 + ks + e;
            w2r[kc][e] = (t < NUM_TYPES) ? (_Float16)W2[(size_t)k * NUM_TYPES + t]
                                         : (_Float16)0.f;
        }
    }
    const int jr = lane & 15;
    const int tb = g * 4;
    float bias[4];
    #pragma unroll
    for (int r = 0; r < 4; ++r)
        bias[r] = (tb + r < NUM_TYPES) ? b2[tb + r] : 0.f;

    __syncthreads();

    // ---- hj fragments: preload all 8 kc once, reuse for all 8 i ----
    const _Float16* hjp = hjs + (jg * 16 + jr) * 520 + ks;
    f16x8 hjr[8];
    #pragma unroll
    for (int kc = 0; kc < 8; ++kc)
        hjr[kc] = *(const f16x8*)(hjp + kc * 32);

    const _Float16* Hi = Hi16 + (size_t)(b * NLANES + i0 + ig * 8) * D_MODEL + ks;

    #pragma unroll
    for (int p = 0; p < 2; ++p) {
        floatx4 acc[4];
        #pragma unroll
        for (int u = 0; u < 4; ++u) acc[u] = (floatx4){0.f, 0.f, 0.f, 0.f};

        #pragma unroll
        for (int u = 0; u < 4; ++u) {
            const _Float16* hi = Hi + (size_t)(p * 4 + u) * D_MODEL;
            f16x8 hir[8];                       // 8 loads issued together
            #pragma unroll
            for (int kc = 0; kc < 8; ++kc)
                hir[kc] = *(const f16x8*)(hi + kc * 32);
            #pragma unroll
            for (int kc = 0; kc < 8; ++kc) {
                f16x8 s = hir[kc] + hjr[kc];    // 4x v_pk_add_f16
                const f16x8 z = {};
                s = __builtin_elementwise_max(s, z);  // 4x v_pk_max_f16
                acc[u] = __builtin_amdgcn_mfma_f32_16x16x32_f16(w2r[kc], s, acc[u], 0, 0, 0);
            }
        }

        // ---- store: lane<32 holds D[tb..tb+3][jr] ----
        if (lane < 32) {
            #pragma unroll
            for (int u = 0; u < 4; ++u) {
                const int i = i0 + ig * 8 + p * 4 + u;
                float* op = out + ((size_t)(b * NLANES + i) * NLANES
                                   + (j0 + jg * 16 + jr)) * NUM_TYPES + tb;
                if (tb == 0) {
                    float v4[4] = { acc[u][0] + bias[0], acc[u][1] + bias[1],
                                    acc[u][2] + bias[2], acc[u][3] + bias[3] };
                    __builtin_memcpy(op, v4, 16);
                } else {
                    float v2[2] = { acc[u][0] + bias[0], acc[u][1] + bias[1] };
                    __builtin_memcpy(op, v2, 8);
                    op[2] = acc[u][2] + bias[2];
                }
            }
        }
    }
}

extern "C" void kernel_launch(void* const* d_in, const int* in_sizes, int n_in,
                              void* d_out, int out_size, void* d_ws, size_t ws_size,
                              hipStream_t stream) {
    const float* x  = (const float*)d_in[0];   // (2,512,256)
    const float* W1 = (const float*)d_in[1];   // (512,256)
    const float* b1 = (const float*)d_in[2];   // (256)
    const float* W2 = (const float*)d_in[3];   // (256,7)
    const float* b2 = (const float*)d_in[4];   // (7)
    float* out = (float*)d_out;                // (2,512,512,7) fp32

    char* ws = (char*)d_ws;
    _Float16* Hi16 = (_Float16*)ws;
    _Float16* Hj16 = (_Float16*)(ws + 512u * 1024u);

    k1_mfma<<<dim3(32, 16), 256, 0, stream>>>(x, W1, b1, Hi16, Hj16);
    k2_pair<<<dim3(NLANES / 32, NLANES / 32, BATCH), 512, 0, stream>>>(
        Hi16, Hj16, W2, b2, out);
}

// Round 7
// 29.747 us; speedup vs baseline: 1.2156x; 1.2156x over previous
//
#include <hip/hip_runtime.h>

#define D_MODEL   256
#define NUM_TYPES 7
#define BATCH     2
#define NLANES    512
#define LSTR      264   // f16 row stride (256 + 8): rows 528B apart -> 2-way bank (free)

typedef _Float16  f16x8   __attribute__((ext_vector_type(8)));
typedef float     floatx4 __attribute__((ext_vector_type(4)));

// Fully fused: out[b,i,j,:] = relu((x@W1a+b1)[i] + (x@W1b)[j]) @ W2 + b2
// Block: 32 i x 64 j. Phase A: recompute the 96 needed H-rows (32 Hi + 64 Hj)
// in LDS via f16 MFMA (x staged f32->f16 in LDS; W1 frags strided->regs, once).
// Phase B: pair stage, all operands from LDS/regs (r5-proven inner loop).
// mfma_f32_16x16x32_f16 layouts (HW-verified earlier rounds):
//   A[row][k]: row=lane&15, k=(lane>>4)*8+e ; B[k][col]: col=lane&15, same k
//   D[row][col]: col=lane&15, row=(lane>>4)*4+r
__global__ __launch_bounds__(512, 2) void k_fused(
    const float* __restrict__ x, const float* __restrict__ W1,
    const float* __restrict__ b1, const float* __restrict__ W2,
    const float* __restrict__ b2, float* __restrict__ out)
{
    __shared__ _Float16 xls[96][LSTR];  // rows 0..31: x[i0+r]; 32..95: x[j0+r-32]
    __shared__ _Float16 Hs [96][LSTR];  // rows 0..31: Hi(+b1);  32..95: Hj

    const int tid  = threadIdx.x;               // 0..511
    const int lane = tid & 63, w = tid >> 6;    // 8 waves
    const int b    = blockIdx.z;
    const int j0   = blockIdx.x * 64;
    const int i0   = blockIdx.y * 32;
    const int jr   = lane & 15, g = lane >> 4, ks = g * 8;

    // ---- stage x rows (96 x 256 f32 -> f16), coalesced ----
    #pragma unroll
    for (int it = 0; it < 6; ++it) {
        const int gg = tid + it * 512;          // granule 0..3071
        const int r  = gg >> 5;                 // row 0..95
        const int c  = (gg & 31) * 8;           // f16 col
        const int srow = (r < 32) ? (i0 + r) : (j0 + (r - 32));
        const float* p = x + (size_t)(b * NLANES + srow) * D_MODEL + c;
        const float4 v0 = *(const float4*)p;
        const float4 v1 = *(const float4*)(p + 4);
        f16x8 o;
        o[0] = (_Float16)v0.x; o[1] = (_Float16)v0.y;
        o[2] = (_Float16)v0.z; o[3] = (_Float16)v0.w;
        o[4] = (_Float16)v1.x; o[5] = (_Float16)v1.y;
        o[6] = (_Float16)v1.z; o[7] = (_Float16)v1.w;
        *(f16x8*)&xls[r][c] = o;
    }

    const int nt0 = w * 2;                      // wave owns n-tiles {nt0, nt0+1}

    __syncthreads();

    // ---- phase A: H rows -> Hs ----
    #pragma unroll 1
    for (int half = 0; half < 2; ++half) {      // 0: Hi rows (W1a,+b1), 1: Hj rows (W1b)
        f16x8 w1f[2][8];                        // [ntx][kc], loaded once per half
        #pragma unroll
        for (int ntx = 0; ntx < 2; ++ntx) {
            const float* wp = W1 + (size_t)(half * D_MODEL + ks) * D_MODEL
                            + (nt0 + ntx) * 16 + jr;
            #pragma unroll
            for (int kc = 0; kc < 8; ++kc)
                #pragma unroll
                for (int e = 0; e < 8; ++e)
                    w1f[ntx][kc][e] = (_Float16)wp[(size_t)(kc * 32 + e) * D_MODEL];
        }
        const int rt_lo = half ? 2 : 0;         // row-tiles: 0..1 = Hi, 2..5 = Hj
        const int rt_n  = half ? 4 : 2;
        for (int rr = 0; rr < rt_n; ++rr) {
            const int rt = rt_lo + rr;
            f16x8 afr[8];
            #pragma unroll
            for (int kc = 0; kc < 8; ++kc)
                afr[kc] = *(const f16x8*)&xls[rt * 16 + jr][kc * 32 + ks];
            #pragma unroll
            for (int ntx = 0; ntx < 2; ++ntx) {
                floatx4 acc = {0.f, 0.f, 0.f, 0.f};
                #pragma unroll
                for (int kc = 0; kc < 8; ++kc)
                    acc = __builtin_amdgcn_mfma_f32_16x16x32_f16(
                        afr[kc], w1f[ntx][kc], acc, 0, 0, 0);
                const float bias = half ? 0.f : b1[(nt0 + ntx) * 16 + jr];
                #pragma unroll
                for (int r = 0; r < 4; ++r)
                    Hs[rt * 16 + g * 4 + r][(nt0 + ntx) * 16 + jr] =
                        (_Float16)(acc[r] + bias);
            }
        }
    }

    // ---- W2^T frags + b2 (independent of Hs; overlaps) ----
    f16x8 w2r[8];
    #pragma unroll
    for (int kc = 0; kc < 8; ++kc)
        #pragma unroll
        for (int e = 0; e < 8; ++e) {
            const int k = kc * 32 + ks + e;
            w2r[kc][e] = (jr < NUM_TYPES)
                ? (_Float16)W2[(size_t)k * NUM_TYPES + jr] : (_Float16)0.f;
        }
    const int tb = g * 4;
    float bias2[4];
    #pragma unroll
    for (int r = 0; r < 4; ++r)
        bias2[r] = (tb + r < NUM_TYPES) ? b2[tb + r] : 0.f;

    __syncthreads();

    // ---- phase B: pair stage. wave = (jg: 16 j's, ig: 16 i's) ----
    const int jg = w & 3, ig = w >> 2;
    f16x8 hjr[8];                               // wave's j-frags, resident
    #pragma unroll
    for (int kc = 0; kc < 8; ++kc)
        hjr[kc] = *(const f16x8*)&Hs[32 + jg * 16 + jr][kc * 32 + ks];

    #pragma unroll 1
    for (int p = 0; p < 2; ++p) {
        floatx4 acc[8];
        #pragma unroll
        for (int u = 0; u < 8; ++u) acc[u] = (floatx4){0.f, 0.f, 0.f, 0.f};
        #pragma unroll
        for (int u = 0; u < 8; ++u) {
            const int il = ig * 16 + p * 8 + u;
            f16x8 hir[8];
            #pragma unroll
            for (int kc = 0; kc < 8; ++kc)
                hir[kc] = *(const f16x8*)&Hs[il][kc * 32 + ks];   // broadcast reads
            #pragma unroll
            for (int kc = 0; kc < 8; ++kc) {
                f16x8 s = hir[kc] + hjr[kc];                      // v_pk_add_f16
                const f16x8 z = {};
                s = __builtin_elementwise_max(s, z);              // v_pk_max_f16
                acc[u] = __builtin_amdgcn_mfma_f32_16x16x32_f16(w2r[kc], s, acc[u], 0, 0, 0);
            }
        }
        // store: lane<32 holds D[tb..tb+3][jr] (proven exact-WRITE pattern)
        if (lane < 32) {
            #pragma unroll
            for (int u = 0; u < 8; ++u) {
                const int i = i0 + ig * 16 + p * 8 + u;
                const int j = j0 + jg * 16 + jr;
                float* op = out + ((size_t)(b * NLANES + i) * NLANES + j) * NUM_TYPES + tb;
                if (tb == 0) {
                    float v4[4] = { acc[u][0] + bias2[0], acc[u][1] + bias2[1],
                                    acc[u][2] + bias2[2], acc[u][3] + bias2[3] };
                    __builtin_memcpy(op, v4, 16);
                } else {
                    float v2[2] = { acc[u][0] + bias2[0], acc[u][1] + bias2[1] };
                    __builtin_memcpy(op, v2, 8);
                    op[2] = acc[u][2] + bias2[2];
                }
            }
        }
    }
}

extern "C" void kernel_launch(void* const* d_in, const int* in_sizes, int n_in,
                              void* d_out, int out_size, void* d_ws, size_t ws_size,
                              hipStream_t stream) {
    const float* x  = (const float*)d_in[0];   // (2,512,256)
    const float* W1 = (const float*)d_in[1];   // (512,256)
    const float* b1 = (const float*)d_in[2];   // (256)
    const float* W2 = (const float*)d_in[3];   // (256,7)
    const float* b2 = (const float*)d_in[4];   // (7)
    float* out = (float*)d_out;                // (2,512,512,7) fp32

    // grid: (j-tiles of 64, i-tiles of 32, batch) = (8,16,2) = 256 blocks
    k_fused<<<dim3(NLANES / 64, NLANES / 32, BATCH), 512, 0, stream>>>(
        x, W1, b1, W2, b2, out);
}

// Round 8
// 27.519 us; speedup vs baseline: 1.3141x; 1.0810x over previous
//
#include <hip/hip_runtime.h>

#define D_MODEL   256
#define NUM_TYPES 7
#define BATCH     2
#define NLANES    512
#define LSTR      264   // f16 LDS row stride: 528B/row -> bank offset +4/row, 2-way max (free)

typedef _Float16  f16x8   __attribute__((ext_vector_type(8)));
typedef float     floatx4 __attribute__((ext_vector_type(4)));

// ws: Hi16 @ 0 (1024*256 f16 = 512 KB) = (x@W1a+b1); Hj16 @ 512 KB = (x@W1b).

// ---------------- Kernel 1: H16 = f16(x @ [W1a|W1b] (+b1)) via f16 MFMA ----------
// (unchanged, r5-proven)
__global__ __launch_bounds__(256) void k1_mfma(
    const float* __restrict__ x, const float* __restrict__ W1,
    const float* __restrict__ b1, _Float16* __restrict__ Hi16,
    _Float16* __restrict__ Hj16)
{
    const int tid  = threadIdx.x, lane = tid & 63, w = tid >> 6;
    const int nt   = blockIdx.x;                  // 0..31 ; half = nt>>4
    const int half = nt >> 4;
    const int nc   = (nt & 15) * 16;
    const int m0   = (blockIdx.y * 4 + w) * 16;
    const int jr   = lane & 15, g = lane >> 4, ks = g * 8;

    const float* xrow = x + (size_t)(m0 + jr) * D_MODEL + ks;
    const float* wb   = W1 + (size_t)(half * D_MODEL + ks) * D_MODEL + nc + jr;

    floatx4 acc = {0.f, 0.f, 0.f, 0.f};
    #pragma unroll
    for (int kc = 0; kc < 8; ++kc) {
        const float4 qa = *(const float4*)(xrow + kc * 32);
        const float4 qb = *(const float4*)(xrow + kc * 32 + 4);
        f16x8 a, bfr;
        a[0] = (_Float16)qa.x; a[1] = (_Float16)qa.y;
        a[2] = (_Float16)qa.z; a[3] = (_Float16)qa.w;
        a[4] = (_Float16)qb.x; a[5] = (_Float16)qb.y;
        a[6] = (_Float16)qb.z; a[7] = (_Float16)qb.w;
        const float* wp = wb + (size_t)(kc * 32) * D_MODEL;
        #pragma unroll
        for (int e = 0; e < 8; ++e)
            bfr[e] = (_Float16)wp[(size_t)e * D_MODEL];
        acc = __builtin_amdgcn_mfma_f32_16x16x32_f16(a, bfr, acc, 0, 0, 0);
    }

    _Float16* Hb = half ? Hj16 : Hi16;
    const float bias = half ? 0.f : b1[nc + jr];
    #pragma unroll
    for (int r = 0; r < 4; ++r)
        Hb[(size_t)(m0 + g * 4 + r) * D_MODEL + nc + jr] = (_Float16)(acc[r] + bias);
}

// ---------------- Kernel 2: out[b,i,j,:] = relu(Hi[i]+Hj[j]) @ W2 + b2 ----------
// Tile 16i x 32j, 256 thr = 4 waves, grid (16,32,2) = 1024 blocks (~4/CU).
// LDS: 48 H-rows (16 Hi + 32 Hj) f16, 25 KB -> high occupancy.
// Wave = ig (4 i's) x BOTH j-groups resident: each broadcast hir read feeds 2 MFMAs.
// kc processed in 2 halves (hjr[2][4], hir[4]) to keep VGPR <= ~128.
__global__ __launch_bounds__(256, 4) void k2_pair(
    const _Float16* __restrict__ Hi16, const _Float16* __restrict__ Hj16,
    const float* __restrict__ W2, const float* __restrict__ b2,
    float* __restrict__ out)
{
    __shared__ _Float16 hs[48][LSTR];   // rows 0..15: Hi(i0+r); 16..47: Hj(j0+r-16)

    const int tid  = threadIdx.x;       // 0..255
    const int lane = tid & 63, w = tid >> 6;
    const int b    = blockIdx.z;
    const int j0   = blockIdx.x * 32;
    const int i0   = blockIdx.y * 16;
    const int jr   = lane & 15, g = lane >> 4, ks = g * 8;

    // ---- stage 48 rows (24 KB of H), 6 x 16B per thread, coalesced ----
    #pragma unroll
    for (int q = 0; q < 6; ++q) {
        const int gg = tid + q * 256;   // granule 0..1535
        const int r  = gg >> 5;         // row 0..47
        const int c  = (gg & 31) * 8;   // f16 col
        const _Float16* src = (r < 16)
            ? Hi16 + (size_t)(b * NLANES + i0 + r) * D_MODEL + c
            : Hj16 + (size_t)(b * NLANES + j0 + (r - 16)) * D_MODEL + c;
        *(f16x8*)&hs[r][c] = *(const f16x8*)src;
    }

    // ---- W2^T A-frags + b2 (global, L2-hot; overlaps staging) ----
    f16x8 w2r[8];
    #pragma unroll
    for (int kc = 0; kc < 8; ++kc)
        #pragma unroll
        for (int e = 0; e < 8; ++e) {
            const int k = kc * 32 + ks + e;
            w2r[kc][e] = (jr < NUM_TYPES)
                ? (_Float16)W2[(size_t)k * NUM_TYPES + jr] : (_Float16)0.f;
        }
    const int tb = g * 4;
    float bias2[4];
    #pragma unroll
    for (int r = 0; r < 4; ++r)
        bias2[r] = (tb + r < NUM_TYPES) ? b2[tb + r] : 0.f;

    __syncthreads();

    const int ig = w;                   // wave's 4 i's: i0 + ig*4 + u
    floatx4 acc[4][2];
    #pragma unroll
    for (int u = 0; u < 4; ++u)
        #pragma unroll
        for (int jg = 0; jg < 2; ++jg)
            acc[u][jg] = (floatx4){0.f, 0.f, 0.f, 0.f};

    #pragma unroll
    for (int kch = 0; kch < 2; ++kch) {
        // hj frags for both j-groups, this k-half (8 ds_read_b128, 2-way max)
        f16x8 hjr[2][4];
        #pragma unroll
        for (int jg = 0; jg < 2; ++jg)
            #pragma unroll
            for (int kc = 0; kc < 4; ++kc)
                hjr[jg][kc] = *(const f16x8*)
                    &hs[16 + jg * 16 + jr][(kch * 4 + kc) * 32 + ks];

        #pragma unroll
        for (int u = 0; u < 4; ++u) {
            f16x8 hir[4];               // broadcast reads (same addr in 16-group)
            #pragma unroll
            for (int kc = 0; kc < 4; ++kc)
                hir[kc] = *(const f16x8*)
                    &hs[ig * 4 + u][(kch * 4 + kc) * 32 + ks];
            #pragma unroll
            for (int kc = 0; kc < 4; ++kc) {
                const f16x8 z = {};
                f16x8 s0 = hir[kc] + hjr[0][kc];
                s0 = __builtin_elementwise_max(s0, z);
                acc[u][0] = __builtin_amdgcn_mfma_f32_16x16x32_f16(
                    w2r[kch * 4 + kc], s0, acc[u][0], 0, 0, 0);
                f16x8 s1 = hir[kc] + hjr[1][kc];
                s1 = __builtin_elementwise_max(s1, z);
                acc[u][1] = __builtin_amdgcn_mfma_f32_16x16x32_f16(
                    w2r[kch * 4 + kc], s1, acc[u][1], 0, 0, 0);
            }
        }
    }

    // ---- store: lane<32 holds D[tb..tb+3][jr] (exact-WRITE pattern) ----
    if (lane < 32) {
        #pragma unroll
        for (int u = 0; u < 4; ++u) {
            const int i = i0 + ig * 4 + u;
            #pragma unroll
            for (int jg = 0; jg < 2; ++jg) {
                const int j = j0 + jg * 16 + jr;
                float* op = out + ((size_t)(b * NLANES + i) * NLANES + j) * NUM_TYPES + tb;
                if (tb == 0) {
                    float v4[4] = { acc[u][jg][0] + bias2[0], acc[u][jg][1] + bias2[1],
                                    acc[u][jg][2] + bias2[2], acc[u][jg][3] + bias2[3] };
                    __builtin_memcpy(op, v4, 16);
                } else {
                    float v2[2] = { acc[u][jg][0] + bias2[0], acc[u][jg][1] + bias2[1] };
                    __builtin_memcpy(op, v2, 8);
                    op[2] = acc[u][jg][2] + bias2[2];
                }
            }
        }
    }
}

extern "C" void kernel_launch(void* const* d_in, const int* in_sizes, int n_in,
                              void* d_out, int out_size, void* d_ws, size_t ws_size,
                              hipStream_t stream) {
    const float* x  = (const float*)d_in[0];   // (2,512,256)
    const float* W1 = (const float*)d_in[1];   // (512,256)
    const float* b1 = (const float*)d_in[2];   // (256)
    const float* W2 = (const float*)d_in[3];   // (256,7)
    const float* b2 = (const float*)d_in[4];   // (7)
    float* out = (float*)d_out;                // (2,512,512,7) fp32

    char* ws = (char*)d_ws;
    _Float16* Hi16 = (_Float16*)ws;
    _Float16* Hj16 = (_Float16*)(ws + 512u * 1024u);

    k1_mfma<<<dim3(32, 16), 256, 0, stream>>>(x, W1, b1, Hi16, Hj16);
    k2_pair<<<dim3(NLANES / 32, NLANES / 16, BATCH), 256, 0, stream>>>(
        Hi16, Hj16, W2, b2, out);
}

// Round 9
// 22.607 us; speedup vs baseline: 1.5996x; 1.2173x over previous
//
#include <hip/hip_runtime.h>

#define D_MODEL   256
#define NUM_TYPES 7
#define BATCH     2
#define NLANES    512
#define LSTR      264   // f16 LDS row stride: 528B/row -> 2-way bank max (free, m136)

typedef _Float16  f16x8   __attribute__((ext_vector_type(8)));
typedef float     floatx4 __attribute__((ext_vector_type(4)));

// ws: Hi16 @ 0 (512 KB) = f16(x@W1a+b1); Hj16 @ 512 KB (512 KB) = f16(x@W1b);
//     w2f @ 1 MB (8 KB) = W2^T MFMA A-fragments (slot = kc*64+lane, f16x8 each).

// ---------------- Kernel 1: H16 = f16(x @ [W1a|W1b] (+b1)) via f16 MFMA ----------
// (r5-proven; one block additionally writes the w2 fragment table)
__global__ __launch_bounds__(256) void k1_mfma(
    const float* __restrict__ x, const float* __restrict__ W1,
    const float* __restrict__ b1, const float* __restrict__ W2,
    _Float16* __restrict__ Hi16, _Float16* __restrict__ Hj16,
    _Float16* __restrict__ w2f)
{
    const int tid  = threadIdx.x, lane = tid & 63, w = tid >> 6;
    const int nt   = blockIdx.x;                  // 0..31 ; half = nt>>4
    const int half = nt >> 4;
    const int nc   = (nt & 15) * 16;
    const int m0   = (blockIdx.y * 4 + w) * 16;
    const int jr   = lane & 15, g = lane >> 4, ks = g * 8;

    const float* xrow = x + (size_t)(m0 + jr) * D_MODEL + ks;
    const float* wb   = W1 + (size_t)(half * D_MODEL + ks) * D_MODEL + nc + jr;

    floatx4 acc = {0.f, 0.f, 0.f, 0.f};
    #pragma unroll
    for (int kc = 0; kc < 8; ++kc) {
        const float4 qa = *(const float4*)(xrow + kc * 32);
        const float4 qb = *(const float4*)(xrow + kc * 32 + 4);
        f16x8 a, bfr;
        a[0] = (_Float16)qa.x; a[1] = (_Float16)qa.y;
        a[2] = (_Float16)qa.z; a[3] = (_Float16)qa.w;
        a[4] = (_Float16)qb.x; a[5] = (_Float16)qb.y;
        a[6] = (_Float16)qb.z; a[7] = (_Float16)qb.w;
        const float* wp = wb + (size_t)(kc * 32) * D_MODEL;
        #pragma unroll
        for (int e = 0; e < 8; ++e)
            bfr[e] = (_Float16)wp[(size_t)e * D_MODEL];
        acc = __builtin_amdgcn_mfma_f32_16x16x32_f16(a, bfr, acc, 0, 0, 0);
    }

    _Float16* Hb = half ? Hj16 : Hi16;
    const float bias = half ? 0.f : b1[nc + jr];
    #pragma unroll
    for (int r = 0; r < 4; ++r)
        Hb[(size_t)(m0 + g * 4 + r) * D_MODEL + nc + jr] = (_Float16)(acc[r] + bias);

    // ---- one block builds the W2^T fragment table (8 KB) ----
    if (nt == 0 && blockIdx.y == 0) {
        #pragma unroll
        for (int s0 = 0; s0 < 2; ++s0) {
            const int s   = tid + s0 * 256;       // slot 0..511
            const int l2  = s & 63, kc2 = s >> 6;
            const int t2  = l2 & 15, ks2 = (l2 >> 4) * 8;
            f16x8 frag;
            #pragma unroll
            for (int e = 0; e < 8; ++e) {
                const int k = kc2 * 32 + ks2 + e;
                frag[e] = (t2 < NUM_TYPES)
                    ? (_Float16)W2[(size_t)k * NUM_TYPES + t2] : (_Float16)0.f;
            }
            *(f16x8*)(w2f + (size_t)s * 8) = frag;
        }
    }
}

// ---------------- Kernel 2: out[b,i,j,:] = relu(Hi[i]+Hj[j]) @ W2 + b2 ----------
// Tile 16i x 32j, 256 thr = 4 waves, grid (16,32,2) = 1024 blocks (~4/CU).
// Wave = 4 i's x BOTH j-groups. Inner loop pipelined: hA/hB ping-pong so each
// ds-latency window hides under the other buffer's 8 MFMA + 16 pk ops.
// w2 frags from precomputed table: 4 coalesced b128 per kch (16 VGPR live).
#define COMPUTE_U(H, U)                                                          \
    do {                                                                         \
        _Pragma("unroll")                                                        \
        for (int kc = 0; kc < 4; ++kc) {                                         \
            const f16x8 z = {};                                                  \
            f16x8 s0 = __builtin_elementwise_max(H[kc] + hjr0[kc], z);           \
            acc##U[0] = __builtin_amdgcn_mfma_f32_16x16x32_f16(                  \
                w2h[kc], s0, acc##U[0], 0, 0, 0);                                \
            f16x8 s1 = __builtin_elementwise_max(H[kc] + hjr1[kc], z);           \
            acc##U[1] = __builtin_amdgcn_mfma_f32_16x16x32_f16(                  \
                w2h[kc], s1, acc##U[1], 0, 0, 0);                                \
        }                                                                        \
    } while (0)

__global__ __launch_bounds__(256, 4) void k2_pair(
    const _Float16* __restrict__ Hi16, const _Float16* __restrict__ Hj16,
    const _Float16* __restrict__ w2f, const float* __restrict__ b2,
    float* __restrict__ out)
{
    __shared__ _Float16 hs[48][LSTR];   // rows 0..15: Hi(i0+r); 16..47: Hj(j0+r-16)

    const int tid  = threadIdx.x;       // 0..255
    const int lane = tid & 63, w = tid >> 6;
    const int b    = blockIdx.z;
    const int j0   = blockIdx.x * 32;
    const int i0   = blockIdx.y * 16;
    const int jr   = lane & 15, g = lane >> 4, ks = g * 8;

    // ---- stage 48 rows (24 KB of H), uniform Hi / Hj halves, coalesced ----
    #pragma unroll
    for (int q = 0; q < 2; ++q) {       // granules 0..511 -> Hi rows 0..15
        const int gg = tid + q * 256;
        const int r  = gg >> 5;
        const int c  = (gg & 31) * 8;
        *(f16x8*)&hs[r][c] = *(const f16x8*)(
            Hi16 + (size_t)(b * NLANES + i0 + r) * D_MODEL + c);
    }
    #pragma unroll
    for (int q = 0; q < 4; ++q) {       // granules 0..1023 -> Hj rows 16..47
        const int gg = tid + q * 256;
        const int r  = gg >> 5;
        const int c  = (gg & 31) * 8;
        *(f16x8*)&hs[16 + r][c] = *(const f16x8*)(
            Hj16 + (size_t)(b * NLANES + j0 + r) * D_MODEL + c);
    }

    const int tb = g * 4;
    float bias2[4];
    #pragma unroll
    for (int r = 0; r < 4; ++r)
        bias2[r] = (tb + r < NUM_TYPES) ? b2[tb + r] : 0.f;

    __syncthreads();

    const int ig = w;                   // wave's 4 i's: i0 + ig*4 + u
    const f16x8* w2fp = (const f16x8*)w2f + lane;   // + (kch*4+kc)*64

    floatx4 acc0[2], acc1[2], acc2[2], acc3[2];
    #pragma unroll
    for (int jg = 0; jg < 2; ++jg) {
        acc0[jg] = (floatx4){0.f, 0.f, 0.f, 0.f};
        acc1[jg] = (floatx4){0.f, 0.f, 0.f, 0.f};
        acc2[jg] = (floatx4){0.f, 0.f, 0.f, 0.f};
        acc3[jg] = (floatx4){0.f, 0.f, 0.f, 0.f};
    }

    #pragma unroll
    for (int kch = 0; kch < 2; ++kch) {
        const int kb = kch * 128;       // f16 col base of this k-half

        f16x8 w2h[4];                   // this half's A-frags: coalesced b128
        #pragma unroll
        for (int kc = 0; kc < 4; ++kc)
            w2h[kc] = w2fp[(kch * 4 + kc) * 64];

        f16x8 hjr0[4], hjr1[4];         // both j-groups, resident
        #pragma unroll
        for (int kc = 0; kc < 4; ++kc) {
            hjr0[kc] = *(const f16x8*)&hs[16 + jr][kb + kc * 32 + ks];
            hjr1[kc] = *(const f16x8*)&hs[32 + jr][kb + kc * 32 + ks];
        }

        f16x8 hA[4], hB[4];             // ping-pong i-fragments
        #pragma unroll
        for (int kc = 0; kc < 4; ++kc)
            hA[kc] = *(const f16x8*)&hs[ig * 4 + 0][kb + kc * 32 + ks];
        #pragma unroll
        for (int kc = 0; kc < 4; ++kc)
            hB[kc] = *(const f16x8*)&hs[ig * 4 + 1][kb + kc * 32 + ks];

        COMPUTE_U(hA, 0);               // u=0
        #pragma unroll
        for (int kc = 0; kc < 4; ++kc)  // refill hA for u=2 (hides under u=1)
            hA[kc] = *(const f16x8*)&hs[ig * 4 + 2][kb + kc * 32 + ks];
        COMPUTE_U(hB, 1);               // u=1
        #pragma unroll
        for (int kc = 0; kc < 4; ++kc)  // refill hB for u=3 (hides under u=2)
            hB[kc] = *(const f16x8*)&hs[ig * 4 + 3][kb + kc * 32 + ks];
        COMPUTE_U(hA, 2);               // u=2
        COMPUTE_U(hB, 3);               // u=3
    }

    // ---- store: lane<32 holds D[tb..tb+3][jr] (proven exact-WRITE pattern) ----
    if (lane < 32) {
        floatx4* accs[4] = {acc0, acc1, acc2, acc3};
        #pragma unroll
        for (int u = 0; u < 4; ++u) {
            const int i = i0 + ig * 4 + u;
            #pragma unroll
            for (int jg = 0; jg < 2; ++jg) {
                const floatx4 a = accs[u][jg];
                const int j = j0 + jg * 16 + jr;
                float* op = out + ((size_t)(b * NLANES + i) * NLANES + j) * NUM_TYPES + tb;
                if (tb == 0) {
                    float v4[4] = { a[0] + bias2[0], a[1] + bias2[1],
                                    a[2] + bias2[2], a[3] + bias2[3] };
                    __builtin_memcpy(op, v4, 16);
                } else {
                    float v2[2] = { a[0] + bias2[0], a[1] + bias2[1] };
                    __builtin_memcpy(op, v2, 8);
                    op[2] = a[2] + bias2[2];
                }
            }
        }
    }
}

extern "C" void kernel_launch(void* const* d_in, const int* in_sizes, int n_in,
                              void* d_out, int out_size, void* d_ws, size_t ws_size,
                              hipStream_t stream) {
    const float* x  = (const float*)d_in[0];   // (2,512,256)
    const float* W1 = (const float*)d_in[1];   // (512,256)
    const float* b1 = (const float*)d_in[2];   // (256)
    const float* W2 = (const float*)d_in[3];   // (256,7)
    const float* b2 = (const float*)d_in[4];   // (7)
    float* out = (float*)d_out;                // (2,512,512,7) fp32

    char* ws = (char*)d_ws;
    _Float16* Hi16 = (_Float16*)ws;
    _Float16* Hj16 = (_Float16*)(ws + 512u * 1024u);
    _Float16* w2f  = (_Float16*)(ws + 1024u * 1024u);

    k1_mfma<<<dim3(32, 16), 256, 0, stream>>>(x, W1, b1, W2, Hi16, Hj16, w2f);
    k2_pair<<<dim3(NLANES / 32, NLANES / 16, BATCH), 256, 0, stream>>>(
        Hi16, Hj16, w2f, b2, out);
}